// Round 1
// baseline (524.258 us; speedup 1.0000x reference)
//
#include <hip/hip_runtime.h>
#include <cstdint>
#include <cstddef>

#define D_MODEL 1024
#define D_FF    2048
#define N_EXP   8
#define NTOK    4096          // B*S
#define NASSIGN (NTOK * 2)    // top-2

typedef __bf16 bf16_t;
typedef bf16_t bf16x8 __attribute__((ext_vector_type(8)));
typedef float  f32x4  __attribute__((ext_vector_type(4)));

typedef __attribute__((address_space(3))) void       lds_void;
typedef const __attribute__((address_space(1))) void gl_void;

__device__ __forceinline__ unsigned short f2b(float f) {
  union { float f; unsigned u; } v; v.f = f;
  unsigned u = v.u;
  unsigned r = (u + 0x7FFFu + ((u >> 16) & 1u)) >> 16;  // RNE
  return (unsigned short)r;
}

// ---------------- Router: fp32 logits, top-2, softmax ----------------
__global__ __launch_bounds__(256) void router_k(
    const float* __restrict__ x, const float* __restrict__ gw,
    int* __restrict__ eidx, float* __restrict__ ewt, int* __restrict__ counts)
{
  const int wv = threadIdx.x >> 6, lane = threadIdx.x & 63;
  const int token = blockIdx.x * 4 + wv;
  const float* xr = x + (size_t)token * D_MODEL;
  const int e  = lane & 7;
  const int dg = lane >> 3;     // 0..7, 128 d's each
  float acc = 0.f;
  #pragma unroll 8
  for (int i = 0; i < 128; ++i) {
    int d = dg * 128 + i;
    acc += xr[d] * gw[d * 8 + e];
  }
  acc += __shfl_xor(acc, 8);
  acc += __shfl_xor(acc, 16);
  acc += __shfl_xor(acc, 32);
  // lane l now holds logit for expert l&7
  float lg[8];
  #pragma unroll
  for (int k = 0; k < 8; ++k) lg[k] = __shfl(acc, k);
  int i1 = 0; float v1 = lg[0];
  #pragma unroll
  for (int k = 1; k < 8; ++k) if (lg[k] > v1) { v1 = lg[k]; i1 = k; }
  int i2 = -1; float v2 = -1e30f;
  #pragma unroll
  for (int k = 0; k < 8; ++k) if (k != i1 && lg[k] > v2) { v2 = lg[k]; i2 = k; }
  float t  = __expf(v2 - v1);
  float w1 = 1.f / (1.f + t);
  float w2 = t * w1;
  if (lane == 0) {
    eidx[token * 2 + 0] = i1; eidx[token * 2 + 1] = i2;
    ewt [token * 2 + 0] = w1; ewt [token * 2 + 1] = w2;
    atomicAdd(&counts[i1], 1);
    atomicAdd(&counts[i2], 1);
  }
}

__global__ void offsets_k(const int* __restrict__ counts, int* __restrict__ offsets) {
  if (threadIdx.x == 0) {
    int o = 0;
    for (int e = 0; e < N_EXP; ++e) { offsets[e] = o; o += counts[e]; }
  }
}

// -------- Gather: assignment -> contiguous per-expert row, x -> bf16 --------
__global__ __launch_bounds__(256) void gather_k(
    const float* __restrict__ x, const int* __restrict__ eidx, const float* __restrict__ ewt,
    const int* __restrict__ offsets, int* __restrict__ fill,
    int* __restrict__ rowtok, float* __restrict__ rowwt, unsigned short* __restrict__ Xe)
{
  __shared__ int srow;
  const int b = blockIdx.x;         // assignment id
  const int token = b >> 1;
  if (threadIdx.x == 0) {
    int e = eidx[b];
    int slot = atomicAdd(&fill[e], 1);
    int row = offsets[e] + slot;
    rowtok[row] = token;
    rowwt[row]  = ewt[b];
    srow = row;
  }
  __syncthreads();
  const int row = srow;
  const float4* xr = (const float4*)(x + (size_t)token * D_MODEL);
  ushort4* dst = (ushort4*)(Xe + (size_t)row * D_MODEL);
  float4 v = xr[threadIdx.x];
  ushort4 o;
  o.x = f2b(v.x); o.y = f2b(v.y); o.z = f2b(v.z); o.w = f2b(v.w);
  dst[threadIdx.x] = o;
}

// ------- Transpose + fp32->bf16: in [e][R][C] -> out [e][C][R] -------
__global__ __launch_bounds__(256) void transcvt_k(
    const float* __restrict__ in, unsigned short* __restrict__ out, int R, int C)
{
  __shared__ float T[32][33];
  const int e = blockIdx.z;
  const float* ein = in + (size_t)e * R * C;
  unsigned short* eout = out + (size_t)e * R * C;
  const int c0 = blockIdx.x * 32, r0 = blockIdx.y * 32;
  const int tx = threadIdx.x & 31, ty = threadIdx.x >> 5;   // ty 0..7
  #pragma unroll
  for (int i = 0; i < 4; ++i) {
    int rr = ty + i * 8;
    T[rr][tx] = ein[(size_t)(r0 + rr) * C + c0 + tx];
  }
  __syncthreads();
  #pragma unroll
  for (int i = 0; i < 4; ++i) {
    int cc = ty + i * 8;
    eout[(size_t)(c0 + cc) * R + r0 + tx] = f2b(T[tx][cc]);
  }
}

// ---------------- Segmented bf16 MFMA GEMM, 128x128x32 tiles ----------------
// A: [rows][K] bf16 (gathered segments). Bt: [E][N][K] bf16 (k-contiguous).
// MODE 1: Hout[row][N] = bf16(silu(A.Bt^T))    MODE 2: atomicAdd(out[token], w * A.Bt^T)
template<int K, int N, int MODE>
__global__ __launch_bounds__(256) void moe_gemm_k(
    const unsigned short* __restrict__ A,
    const unsigned short* __restrict__ Bt,
    unsigned short* __restrict__ Hout,
    float* __restrict__ out,
    const int* __restrict__ counts, const int* __restrict__ offsets,
    const int* __restrict__ rowtok, const float* __restrict__ rowwt)
{
  const int e = blockIdx.z;
  const int cnt = counts[e];
  const int m0 = blockIdx.y * 128;
  if (m0 >= cnt) return;
  const int base = offsets[e];
  const int n0 = blockIdx.x * 128;

  __shared__ unsigned short lA[128 * 32];
  __shared__ unsigned short lB[128 * 32];

  const int tid = threadIdx.x;
  const int lane = tid & 63;
  const int wv = tid >> 6;
  const int wm = wv & 1, wn = wv >> 1;
  const int col = lane & 15, quad = lane >> 4;

  const unsigned short* Aseg = A + (size_t)base * K;
  const unsigned short* Bseg = Bt + (size_t)e * ((size_t)N * K);

  f32x4 acc[4][4] = {};

  for (int k0 = 0; k0 < K; k0 += 32) {
    __syncthreads();
    #pragma unroll
    for (int r = 0; r < 2; ++r) {
      int flat = ((r * 4 + wv) * 64 + lane) * 16;   // byte offset within 8KB tile
      int row = flat >> 6;                          // 64B per (row, 32 k) slice
      int kb  = flat & 63;
      const char* gA = (const char*)Aseg + ((size_t)(m0 + row) * K + k0) * 2 + kb;
      const char* gB = (const char*)Bseg + ((size_t)(n0 + row) * K + k0) * 2 + kb;
      char* lpa = (char*)lA + (r * 4 + wv) * 1024;
      char* lpb = (char*)lB + (r * 4 + wv) * 1024;
      __builtin_amdgcn_global_load_lds((gl_void*)gA, (lds_void*)lpa, 16, 0, 0);
      __builtin_amdgcn_global_load_lds((gl_void*)gB, (lds_void*)lpb, 16, 0, 0);
    }
    __syncthreads();

    bf16x8 af[4], bfr[4];
    #pragma unroll
    for (int i = 0; i < 4; ++i)
      af[i] = *(const bf16x8*)(lA + ((wm * 64 + i * 16 + col) * 32 + quad * 8));
    #pragma unroll
    for (int j = 0; j < 4; ++j)
      bfr[j] = *(const bf16x8*)(lB + ((wn * 64 + j * 16 + col) * 32 + quad * 8));
    #pragma unroll
    for (int i = 0; i < 4; ++i)
      #pragma unroll
      for (int j = 0; j < 4; ++j)
        acc[i][j] = __builtin_amdgcn_mfma_f32_16x16x32_bf16(af[i], bfr[j], acc[i][j], 0, 0, 0);
  }

  // Epilogue. C/D layout: col = lane&15, row = quad*4 + reg  [m89/m91 verified]
  #pragma unroll
  for (int i = 0; i < 4; ++i) {
    #pragma unroll
    for (int reg = 0; reg < 4; ++reg) {
      int r = m0 + wm * 64 + i * 16 + quad * 4 + reg;
      if (r < cnt) {
        if (MODE == 1) {
          unsigned short* hrow = Hout + (size_t)(base + r) * N + (n0 + wn * 64 + col);
          #pragma unroll
          for (int j = 0; j < 4; ++j) {
            float v = acc[i][j][reg];
            float s = v / (1.f + __expf(-v));   // silu
            hrow[j * 16] = f2b(s);
          }
        } else {
          int   token = rowtok[base + r];
          float wgt   = rowwt[base + r];
          float* orow = out + (size_t)token * D_MODEL + (n0 + wn * 64 + col);
          #pragma unroll
          for (int j = 0; j < 4; ++j)
            atomicAdd(&orow[j * 16], wgt * acc[i][j][reg]);
        }
      }
    }
  }
}

extern "C" void kernel_launch(void* const* d_in, const int* in_sizes, int n_in,
                              void* d_out, int out_size, void* d_ws, size_t ws_size,
                              hipStream_t stream) {
  const float* x  = (const float*)d_in[0];
  const float* gw = (const float*)d_in[1];
  const float* w1 = (const float*)d_in[2];
  const float* w2 = (const float*)d_in[3];
  float* out = (float*)d_out;

  char* ws = (char*)d_ws;
  size_t off = 0;
  auto alloc = [&](size_t bytes) -> char* {
    char* p = ws + off; off += (bytes + 255) & ~(size_t)255; return p;
  };
  int*   ctrl    = (int*)alloc(256);      // counts[8] | fill[8] | offsets[8]
  int*   counts  = ctrl;
  int*   fill    = ctrl + 8;
  int*   offsets = ctrl + 16;
  int*   eidx    = (int*)  alloc((size_t)NASSIGN * 4);
  float* ewt     = (float*)alloc((size_t)NASSIGN * 4);
  int*   rowtok  = (int*)  alloc((size_t)NASSIGN * 4);
  float* rowwt   = (float*)alloc((size_t)NASSIGN * 4);
  unsigned short* Xe  = (unsigned short*)alloc((size_t)(NASSIGN + 128) * D_MODEL * 2);
  unsigned short* H   = (unsigned short*)alloc((size_t)(NASSIGN + 128) * D_FF * 2);
  unsigned short* w1t = (unsigned short*)alloc((size_t)N_EXP * D_MODEL * D_FF * 2);
  unsigned short* w2t = (unsigned short*)alloc((size_t)N_EXP * D_MODEL * D_FF * 2);

  hipMemsetAsync(ctrl, 0, 256, stream);
  hipMemsetAsync(d_out, 0, (size_t)out_size * sizeof(float), stream);

  router_k<<<NTOK / 4, 256, 0, stream>>>(x, gw, eidx, ewt, counts);
  offsets_k<<<1, 64, 0, stream>>>(counts, offsets);
  gather_k<<<NASSIGN, 256, 0, stream>>>(x, eidx, ewt, offsets, fill, rowtok, rowwt, Xe);
  transcvt_k<<<dim3(D_FF / 32, D_MODEL / 32, N_EXP), 256, 0, stream>>>(w1, w1t, D_MODEL, D_FF);
  transcvt_k<<<dim3(D_MODEL / 32, D_FF / 32, N_EXP), 256, 0, stream>>>(w2, w2t, D_FF, D_MODEL);

  moe_gemm_k<D_MODEL, D_FF, 1><<<dim3(D_FF / 128, 32, N_EXP), 256, 0, stream>>>(
      Xe, w1t, H, nullptr, counts, offsets, rowtok, rowwt);
  moe_gemm_k<D_FF, D_MODEL, 2><<<dim3(D_MODEL / 128, 32, N_EXP), 256, 0, stream>>>(
      H, w2t, nullptr, out, counts, offsets, rowtok, rowwt);
}

// Round 2
// 520.711 us; speedup vs baseline: 1.0068x; 1.0068x over previous
//
#include <hip/hip_runtime.h>
#include <cstdint>
#include <cstddef>

#define D_MODEL 1024
#define D_FF    2048
#define N_EXP   8
#define NTOK    4096          // B*S
#define NASSIGN (NTOK * 2)    // top-2

typedef __bf16 bf16_t;
typedef bf16_t bf16x8 __attribute__((ext_vector_type(8)));
typedef float  f32x4  __attribute__((ext_vector_type(4)));

typedef __attribute__((address_space(3))) void       lds_void;
typedef const __attribute__((address_space(1))) void gl_void;

__device__ __forceinline__ unsigned short f2b(float f) {
  union { float f; unsigned u; } v; v.f = f;
  unsigned u = v.u;
  unsigned r = (u + 0x7FFFu + ((u >> 16) & 1u)) >> 16;  // RNE
  return (unsigned short)r;
}

// ---------------- Router: fp32 logits, top-2, softmax ----------------
// Wave per token. Lane l loads x[token][it*256 + l*4 ..] as float4 (coalesced,
// whole row in 4 loads), gw rows from global (32 KB, L1-resident), 8 accs/lane,
// butterfly reduce.
__global__ __launch_bounds__(256) void router_k(
    const float* __restrict__ x, const float* __restrict__ gw,
    int* __restrict__ eidx, float* __restrict__ ewt, int* __restrict__ counts)
{
  const int wv = threadIdx.x >> 6, lane = threadIdx.x & 63;
  const int token = blockIdx.x * 4 + wv;
  const float4* xr4 = (const float4*)(x + (size_t)token * D_MODEL);
  const float4* gw4 = (const float4*)gw;

  float acc[8] = {};
  #pragma unroll
  for (int it = 0; it < 4; ++it) {
    float4 xv = xr4[it * 64 + lane];
    int d0 = it * 256 + lane * 4;
    #pragma unroll
    for (int i = 0; i < 4; ++i) {
      int d = d0 + i;
      float4 g0 = gw4[d * 2];
      float4 g1 = gw4[d * 2 + 1];
      float xs = (i == 0) ? xv.x : (i == 1) ? xv.y : (i == 2) ? xv.z : xv.w;
      acc[0] += xs * g0.x; acc[1] += xs * g0.y;
      acc[2] += xs * g0.z; acc[3] += xs * g0.w;
      acc[4] += xs * g1.x; acc[5] += xs * g1.y;
      acc[6] += xs * g1.z; acc[7] += xs * g1.w;
    }
  }
  #pragma unroll
  for (int m = 1; m < 64; m <<= 1) {
    #pragma unroll
    for (int k = 0; k < 8; ++k) acc[k] += __shfl_xor(acc[k], m);
  }
  if (lane == 0) {
    int i1 = 0; float v1 = acc[0];
    #pragma unroll
    for (int k = 1; k < 8; ++k) if (acc[k] > v1) { v1 = acc[k]; i1 = k; }
    int i2 = -1; float v2 = -1e30f;
    #pragma unroll
    for (int k = 0; k < 8; ++k) if (k != i1 && acc[k] > v2) { v2 = acc[k]; i2 = k; }
    float t  = __expf(v2 - v1);
    float w1 = 1.f / (1.f + t);
    float w2 = t * w1;
    eidx[token * 2 + 0] = i1; eidx[token * 2 + 1] = i2;
    ewt [token * 2 + 0] = w1; ewt [token * 2 + 1] = w2;
    atomicAdd(&counts[i1], 1);
    atomicAdd(&counts[i2], 1);
  }
}

__global__ void offsets_k(const int* __restrict__ counts, int* __restrict__ offsets) {
  if (threadIdx.x == 0) {
    int o = 0;
    for (int e = 0; e < N_EXP; ++e) { offsets[e] = o; o += counts[e]; }
  }
}

// -------- Gather: assignment -> contiguous per-expert row, x -> bf16 --------
__global__ __launch_bounds__(256) void gather_k(
    const float* __restrict__ x, const int* __restrict__ eidx, const float* __restrict__ ewt,
    const int* __restrict__ offsets, int* __restrict__ fill,
    int* __restrict__ rowtok, float* __restrict__ rowwt, unsigned short* __restrict__ Xe)
{
  __shared__ int srow;
  const int b = blockIdx.x;         // assignment id
  const int token = b >> 1;
  if (threadIdx.x == 0) {
    int e = eidx[b];
    int slot = atomicAdd(&fill[e], 1);
    int row = offsets[e] + slot;
    rowtok[row] = token;
    rowwt[row]  = ewt[b];
    srow = row;
  }
  __syncthreads();
  const int row = srow;
  const float4* xr = (const float4*)(x + (size_t)token * D_MODEL);
  ushort4* dst = (ushort4*)(Xe + (size_t)row * D_MODEL);
  float4 v = xr[threadIdx.x];
  ushort4 o;
  o.x = f2b(v.x); o.y = f2b(v.y); o.z = f2b(v.z); o.w = f2b(v.w);
  dst[threadIdx.x] = o;
}

// ------- Transpose + fp32->bf16: in [e][R][C] -> out [e][C][R] -------
__global__ __launch_bounds__(256) void transcvt_k(
    const float* __restrict__ in, unsigned short* __restrict__ out, int R, int C)
{
  __shared__ float T[32][33];
  const int e = blockIdx.z;
  const float* ein = in + (size_t)e * R * C;
  unsigned short* eout = out + (size_t)e * R * C;
  const int c0 = blockIdx.x * 32, r0 = blockIdx.y * 32;
  const int tx = threadIdx.x & 31, ty = threadIdx.x >> 5;   // ty 0..7
  #pragma unroll
  for (int i = 0; i < 4; ++i) {
    int rr = ty + i * 8;
    T[rr][tx] = ein[(size_t)(r0 + rr) * C + c0 + tx];
  }
  __syncthreads();
  #pragma unroll
  for (int i = 0; i < 4; ++i) {
    int cc = ty + i * 8;
    eout[(size_t)(c0 + cc) * R + r0 + tx] = f2b(T[tx][cc]);
  }
}

// ---------------- Segmented bf16 MFMA GEMM, 128x128x32 tiles ----------------
// A: [rows][K] bf16 (gathered segments). Bt: [E][N][K] bf16 (k-contiguous).
// MODE 1: Hout[row][N] = bf16(silu(A.Bt^T))    MODE 2: atomicAdd(out[token], w * A.Bt^T)
template<int K, int N, int MODE>
__global__ __launch_bounds__(256) void moe_gemm_k(
    const unsigned short* __restrict__ A,
    const unsigned short* __restrict__ Bt,
    unsigned short* __restrict__ Hout,
    float* __restrict__ out,
    const int* __restrict__ counts, const int* __restrict__ offsets,
    const int* __restrict__ rowtok, const float* __restrict__ rowwt)
{
  const int e = blockIdx.z;
  const int cnt = counts[e];
  const int m0 = blockIdx.y * 128;
  if (m0 >= cnt) return;
  const int base = offsets[e];
  const int n0 = blockIdx.x * 128;

  __shared__ unsigned short lA[128 * 32];
  __shared__ unsigned short lB[128 * 32];

  const int tid = threadIdx.x;
  const int lane = tid & 63;
  const int wv = tid >> 6;
  const int wm = wv & 1, wn = wv >> 1;
  const int col = lane & 15, quad = lane >> 4;

  const unsigned short* Aseg = A + (size_t)base * K;
  const unsigned short* Bseg = Bt + (size_t)e * ((size_t)N * K);

  f32x4 acc[4][4] = {};

  for (int k0 = 0; k0 < K; k0 += 32) {
    __syncthreads();
    #pragma unroll
    for (int r = 0; r < 2; ++r) {
      int flat = ((r * 4 + wv) * 64 + lane) * 16;   // byte offset within 8KB tile
      int row = flat >> 6;                          // 64B per (row, 32 k) slice
      int kb  = flat & 63;
      const char* gA = (const char*)Aseg + ((size_t)(m0 + row) * K + k0) * 2 + kb;
      const char* gB = (const char*)Bseg + ((size_t)(n0 + row) * K + k0) * 2 + kb;
      char* lpa = (char*)lA + (r * 4 + wv) * 1024;
      char* lpb = (char*)lB + (r * 4 + wv) * 1024;
      __builtin_amdgcn_global_load_lds((gl_void*)gA, (lds_void*)lpa, 16, 0, 0);
      __builtin_amdgcn_global_load_lds((gl_void*)gB, (lds_void*)lpb, 16, 0, 0);
    }
    __syncthreads();

    bf16x8 af[4], bfr[4];
    #pragma unroll
    for (int i = 0; i < 4; ++i)
      af[i] = *(const bf16x8*)(lA + ((wm * 64 + i * 16 + col) * 32 + quad * 8));
    #pragma unroll
    for (int j = 0; j < 4; ++j)
      bfr[j] = *(const bf16x8*)(lB + ((wn * 64 + j * 16 + col) * 32 + quad * 8));
    #pragma unroll
    for (int i = 0; i < 4; ++i)
      #pragma unroll
      for (int j = 0; j < 4; ++j)
        acc[i][j] = __builtin_amdgcn_mfma_f32_16x16x32_bf16(af[i], bfr[j], acc[i][j], 0, 0, 0);
  }

  // Epilogue. C/D layout: col = lane&15, row = quad*4 + reg  [m89/m91 verified]
  #pragma unroll
  for (int i = 0; i < 4; ++i) {
    #pragma unroll
    for (int reg = 0; reg < 4; ++reg) {
      int r = m0 + wm * 64 + i * 16 + quad * 4 + reg;
      if (r < cnt) {
        if (MODE == 1) {
          unsigned short* hrow = Hout + (size_t)(base + r) * N + (n0 + wn * 64 + col);
          #pragma unroll
          for (int j = 0; j < 4; ++j) {
            float v = acc[i][j][reg];
            float s = v / (1.f + __expf(-v));   // silu
            hrow[j * 16] = f2b(s);
          }
        } else {
          int   token = rowtok[base + r];
          float wgt   = rowwt[base + r];
          float* orow = out + (size_t)token * D_MODEL + (n0 + wn * 64 + col);
          #pragma unroll
          for (int j = 0; j < 4; ++j)
            atomicAdd(&orow[j * 16], wgt * acc[i][j][reg]);
        }
      }
    }
  }
}

extern "C" void kernel_launch(void* const* d_in, const int* in_sizes, int n_in,
                              void* d_out, int out_size, void* d_ws, size_t ws_size,
                              hipStream_t stream) {
  const float* x  = (const float*)d_in[0];
  const float* gw = (const float*)d_in[1];
  const float* w1 = (const float*)d_in[2];
  const float* w2 = (const float*)d_in[3];
  float* out = (float*)d_out;

  char* ws = (char*)d_ws;
  size_t off = 0;
  auto alloc = [&](size_t bytes) -> char* {
    char* p = ws + off; off += (bytes + 255) & ~(size_t)255; return p;
  };
  int*   ctrl    = (int*)alloc(256);      // counts[8] | fill[8] | offsets[8]
  int*   counts  = ctrl;
  int*   fill    = ctrl + 8;
  int*   offsets = ctrl + 16;
  int*   eidx    = (int*)  alloc((size_t)NASSIGN * 4);
  float* ewt     = (float*)alloc((size_t)NASSIGN * 4);
  int*   rowtok  = (int*)  alloc((size_t)NASSIGN * 4);
  float* rowwt   = (float*)alloc((size_t)NASSIGN * 4);
  unsigned short* Xe  = (unsigned short*)alloc((size_t)(NASSIGN + 128) * D_MODEL * 2);
  unsigned short* H   = (unsigned short*)alloc((size_t)(NASSIGN + 128) * D_FF * 2);
  unsigned short* w1t = (unsigned short*)alloc((size_t)N_EXP * D_MODEL * D_FF * 2);
  unsigned short* w2t = (unsigned short*)alloc((size_t)N_EXP * D_MODEL * D_FF * 2);

  hipMemsetAsync(ctrl, 0, 256, stream);
  hipMemsetAsync(d_out, 0, (size_t)out_size * sizeof(float), stream);

  router_k<<<NTOK / 4, 256, 0, stream>>>(x, gw, eidx, ewt, counts);
  offsets_k<<<1, 64, 0, stream>>>(counts, offsets);
  gather_k<<<NASSIGN, 256, 0, stream>>>(x, eidx, ewt, offsets, fill, rowtok, rowwt, Xe);
  transcvt_k<<<dim3(D_FF / 32, D_MODEL / 32, N_EXP), 256, 0, stream>>>(w1, w1t, D_MODEL, D_FF);
  transcvt_k<<<dim3(D_MODEL / 32, D_FF / 32, N_EXP), 256, 0, stream>>>(w2, w2t, D_FF, D_MODEL);

  moe_gemm_k<D_MODEL, D_FF, 1><<<dim3(D_FF / 128, 32, N_EXP), 256, 0, stream>>>(
      Xe, w1t, H, nullptr, counts, offsets, rowtok, rowwt);
  moe_gemm_k<D_FF, D_MODEL, 2><<<dim3(D_MODEL / 128, 32, N_EXP), 256, 0, stream>>>(
      H, w2t, nullptr, out, counts, offsets, rowtok, rowwt);
}

// Round 3
// 352.191 us; speedup vs baseline: 1.4886x; 1.4785x over previous
//
#include <hip/hip_runtime.h>
#include <cstdint>
#include <cstddef>

#define D_MODEL 1024
#define D_FF    2048
#define N_EXP   8
#define NTOK    4096          // B*S
#define NASSIGN (NTOK * 2)    // top-2

typedef __bf16 bf16_t;
typedef bf16_t bf16x8 __attribute__((ext_vector_type(8)));
typedef float  f32x4  __attribute__((ext_vector_type(4)));

typedef __attribute__((address_space(3))) void       lds_void;
typedef const __attribute__((address_space(1))) void gl_void;

__device__ __forceinline__ unsigned short f2b(float f) {
  union { float f; unsigned u; } v; v.f = f;
  unsigned u = v.u;
  unsigned r = (u + 0x7FFFu + ((u >> 16) & 1u)) >> 16;  // RNE
  return (unsigned short)r;
}

// ---------------- Router: fp32 logits, top-2, softmax. NO atomics. ----------------
__global__ __launch_bounds__(256) void router_k(
    const float* __restrict__ x, const float* __restrict__ gw,
    int* __restrict__ eidx, float* __restrict__ ewt)
{
  const int wv = threadIdx.x >> 6, lane = threadIdx.x & 63;
  const int token = blockIdx.x * 4 + wv;
  const float4* xr4 = (const float4*)(x + (size_t)token * D_MODEL);
  const float4* gw4 = (const float4*)gw;

  float acc[8] = {};
  #pragma unroll
  for (int it = 0; it < 4; ++it) {
    float4 xv = xr4[it * 64 + lane];
    int d0 = it * 256 + lane * 4;
    #pragma unroll
    for (int i = 0; i < 4; ++i) {
      int d = d0 + i;
      float4 g0 = gw4[d * 2];
      float4 g1 = gw4[d * 2 + 1];
      float xs = (i == 0) ? xv.x : (i == 1) ? xv.y : (i == 2) ? xv.z : xv.w;
      acc[0] += xs * g0.x; acc[1] += xs * g0.y;
      acc[2] += xs * g0.z; acc[3] += xs * g0.w;
      acc[4] += xs * g1.x; acc[5] += xs * g1.y;
      acc[6] += xs * g1.z; acc[7] += xs * g1.w;
    }
  }
  #pragma unroll
  for (int m = 1; m < 64; m <<= 1) {
    #pragma unroll
    for (int k = 0; k < 8; ++k) acc[k] += __shfl_xor(acc[k], m);
  }
  if (lane == 0) {
    int i1 = 0; float v1 = acc[0];
    #pragma unroll
    for (int k = 1; k < 8; ++k) if (acc[k] > v1) { v1 = acc[k]; i1 = k; }
    int i2 = -1; float v2 = -1e30f;
    #pragma unroll
    for (int k = 0; k < 8; ++k) if (k != i1 && acc[k] > v2) { v2 = acc[k]; i2 = k; }
    float t  = __expf(v2 - v1);
    float w1 = 1.f / (1.f + t);
    float w2 = t * w1;
    eidx[token * 2 + 0] = i1; eidx[token * 2 + 1] = i2;
    ewt [token * 2 + 0] = w1; ewt [token * 2 + 1] = w2;
  }
}

// ------- Scan: deterministic per-expert ranking, counts, offsets, row maps -------
// One block, 1024 threads, 8 assignments/thread. LDS Hillis-Steele scan.
__global__ __launch_bounds__(1024) void scan_k(
    const int* __restrict__ eidx, const float* __restrict__ ewt,
    int* __restrict__ counts, int* __restrict__ offsets,
    int* __restrict__ rowtok, float* __restrict__ rowwt)
{
  __shared__ int hist[1024][9];   // stride 9: conflict-free (coprime with 32)
  __shared__ int soff[8];
  const int t = threadIdx.x;

  int myeid[8];
  int pre[8];
  int local[8] = {};
  #pragma unroll
  for (int i = 0; i < 8; ++i) {
    int e = eidx[t * 8 + i];
    myeid[i] = e;
    pre[i] = local[e];
    local[e]++;
  }
  #pragma unroll
  for (int e = 0; e < 8; ++e) hist[t][e] = local[e];
  __syncthreads();

  // inclusive scan over threads, 8 experts in parallel
  for (int ofs = 1; ofs < 1024; ofs <<= 1) {
    int v[8];
    if (t >= ofs) {
      #pragma unroll
      for (int e = 0; e < 8; ++e) v[e] = hist[t - ofs][e];
    }
    __syncthreads();
    if (t >= ofs) {
      #pragma unroll
      for (int e = 0; e < 8; ++e) hist[t][e] += v[e];
    }
    __syncthreads();
  }

  if (t == 0) {
    int o = 0;
    for (int e = 0; e < 8; ++e) {
      int c = hist[1023][e];
      counts[e] = c;
      offsets[e] = o;
      soff[e] = o;
      o += c;
    }
  }
  __syncthreads();

  int excl[8];
  #pragma unroll
  for (int e = 0; e < 8; ++e) excl[e] = hist[t][e] - local[e];

  #pragma unroll
  for (int i = 0; i < 8; ++i) {
    int b = t * 8 + i;
    int e = myeid[i];
    int row = soff[e] + excl[e] + pre[i];
    rowtok[row] = b >> 1;
    rowwt[row]  = ewt[b];
  }
}

// -------- Gather: block per row, x[token] -> bf16 Xe[row]. NO atomics. --------
__global__ __launch_bounds__(256) void gather_k(
    const float* __restrict__ x, const int* __restrict__ rowtok,
    unsigned short* __restrict__ Xe)
{
  const int row = blockIdx.x;
  const int token = rowtok[row];
  const float4* xr = (const float4*)(x + (size_t)token * D_MODEL);
  ushort4* dst = (ushort4*)(Xe + (size_t)row * D_MODEL);
  float4 v = xr[threadIdx.x];
  ushort4 o;
  o.x = f2b(v.x); o.y = f2b(v.y); o.z = f2b(v.z); o.w = f2b(v.w);
  dst[threadIdx.x] = o;
}

// ------- Transpose + fp32->bf16: in [e][R][C] -> out [e][C][R] -------
__global__ __launch_bounds__(256) void transcvt_k(
    const float* __restrict__ in, unsigned short* __restrict__ out, int R, int C)
{
  __shared__ float T[32][33];
  const int e = blockIdx.z;
  const float* ein = in + (size_t)e * R * C;
  unsigned short* eout = out + (size_t)e * R * C;
  const int c0 = blockIdx.x * 32, r0 = blockIdx.y * 32;
  const int tx = threadIdx.x & 31, ty = threadIdx.x >> 5;   // ty 0..7
  #pragma unroll
  for (int i = 0; i < 4; ++i) {
    int rr = ty + i * 8;
    T[rr][tx] = ein[(size_t)(r0 + rr) * C + c0 + tx];
  }
  __syncthreads();
  #pragma unroll
  for (int i = 0; i < 4; ++i) {
    int cc = ty + i * 8;
    eout[(size_t)(c0 + cc) * R + r0 + tx] = f2b(T[tx][cc]);
  }
}

// ---------------- Segmented bf16 MFMA GEMM, 128x128x32 tiles ----------------
// A: [rows][K] bf16 (gathered segments). Bt: [E][N][K] bf16 (k-contiguous).
// MODE 1: Hout[row][N] = bf16(silu(A.Bt^T))    MODE 2: atomicAdd(out[token], w * A.Bt^T)
template<int K, int N, int MODE>
__global__ __launch_bounds__(256) void moe_gemm_k(
    const unsigned short* __restrict__ A,
    const unsigned short* __restrict__ Bt,
    unsigned short* __restrict__ Hout,
    float* __restrict__ out,
    const int* __restrict__ counts, const int* __restrict__ offsets,
    const int* __restrict__ rowtok, const float* __restrict__ rowwt)
{
  const int e = blockIdx.z;
  const int cnt = counts[e];
  const int m0 = blockIdx.y * 128;
  if (m0 >= cnt) return;
  const int base = offsets[e];
  const int n0 = blockIdx.x * 128;

  __shared__ unsigned short lA[128 * 32];
  __shared__ unsigned short lB[128 * 32];

  const int tid = threadIdx.x;
  const int lane = tid & 63;
  const int wv = tid >> 6;
  const int wm = wv & 1, wn = wv >> 1;
  const int col = lane & 15, quad = lane >> 4;

  const unsigned short* Aseg = A + (size_t)base * K;
  const unsigned short* Bseg = Bt + (size_t)e * ((size_t)N * K);

  f32x4 acc[4][4] = {};

  for (int k0 = 0; k0 < K; k0 += 32) {
    __syncthreads();
    #pragma unroll
    for (int r = 0; r < 2; ++r) {
      int flat = ((r * 4 + wv) * 64 + lane) * 16;   // byte offset within 8KB tile
      int row = flat >> 6;                          // 64B per (row, 32 k) slice
      int kb  = flat & 63;
      const char* gA = (const char*)Aseg + ((size_t)(m0 + row) * K + k0) * 2 + kb;
      const char* gB = (const char*)Bseg + ((size_t)(n0 + row) * K + k0) * 2 + kb;
      char* lpa = (char*)lA + (r * 4 + wv) * 1024;
      char* lpb = (char*)lB + (r * 4 + wv) * 1024;
      __builtin_amdgcn_global_load_lds((gl_void*)gA, (lds_void*)lpa, 16, 0, 0);
      __builtin_amdgcn_global_load_lds((gl_void*)gB, (lds_void*)lpb, 16, 0, 0);
    }
    __syncthreads();

    bf16x8 af[4], bfr[4];
    #pragma unroll
    for (int i = 0; i < 4; ++i)
      af[i] = *(const bf16x8*)(lA + ((wm * 64 + i * 16 + col) * 32 + quad * 8));
    #pragma unroll
    for (int j = 0; j < 4; ++j)
      bfr[j] = *(const bf16x8*)(lB + ((wn * 64 + j * 16 + col) * 32 + quad * 8));
    #pragma unroll
    for (int i = 0; i < 4; ++i)
      #pragma unroll
      for (int j = 0; j < 4; ++j)
        acc[i][j] = __builtin_amdgcn_mfma_f32_16x16x32_bf16(af[i], bfr[j], acc[i][j], 0, 0, 0);
  }

  // Epilogue. C/D layout: col = lane&15, row = quad*4 + reg  [m89/m91 verified]
  #pragma unroll
  for (int i = 0; i < 4; ++i) {
    #pragma unroll
    for (int reg = 0; reg < 4; ++reg) {
      int r = m0 + wm * 64 + i * 16 + quad * 4 + reg;
      if (r < cnt) {
        if (MODE == 1) {
          unsigned short* hrow = Hout + (size_t)(base + r) * N + (n0 + wn * 64 + col);
          #pragma unroll
          for (int j = 0; j < 4; ++j) {
            float v = acc[i][j][reg];
            float s = v / (1.f + __expf(-v));   // silu
            hrow[j * 16] = f2b(s);
          }
        } else {
          int   token = rowtok[base + r];
          float wgt   = rowwt[base + r];
          float* orow = out + (size_t)token * D_MODEL + (n0 + wn * 64 + col);
          #pragma unroll
          for (int j = 0; j < 4; ++j)
            atomicAdd(&orow[j * 16], wgt * acc[i][j][reg]);
        }
      }
    }
  }
}

extern "C" void kernel_launch(void* const* d_in, const int* in_sizes, int n_in,
                              void* d_out, int out_size, void* d_ws, size_t ws_size,
                              hipStream_t stream) {
  const float* x  = (const float*)d_in[0];
  const float* gw = (const float*)d_in[1];
  const float* w1 = (const float*)d_in[2];
  const float* w2 = (const float*)d_in[3];
  float* out = (float*)d_out;

  char* ws = (char*)d_ws;
  size_t off = 0;
  auto alloc = [&](size_t bytes) -> char* {
    char* p = ws + off; off += (bytes + 255) & ~(size_t)255; return p;
  };
  int*   ctrl    = (int*)alloc(256);      // counts[8] | offsets[8]
  int*   counts  = ctrl;
  int*   offsets = ctrl + 8;
  int*   eidx    = (int*)  alloc((size_t)NASSIGN * 4);
  float* ewt     = (float*)alloc((size_t)NASSIGN * 4);
  int*   rowtok  = (int*)  alloc((size_t)NASSIGN * 4);
  float* rowwt   = (float*)alloc((size_t)NASSIGN * 4);
  unsigned short* Xe  = (unsigned short*)alloc((size_t)(NASSIGN + 128) * D_MODEL * 2);
  unsigned short* H   = (unsigned short*)alloc((size_t)(NASSIGN + 128) * D_FF * 2);
  unsigned short* w1t = (unsigned short*)alloc((size_t)N_EXP * D_MODEL * D_FF * 2);
  unsigned short* w2t = (unsigned short*)alloc((size_t)N_EXP * D_MODEL * D_FF * 2);

  hipMemsetAsync(d_out, 0, (size_t)out_size * sizeof(float), stream);

  router_k<<<NTOK / 4, 256, 0, stream>>>(x, gw, eidx, ewt);
  scan_k<<<1, 1024, 0, stream>>>(eidx, ewt, counts, offsets, rowtok, rowwt);
  gather_k<<<NASSIGN, 256, 0, stream>>>(x, rowtok, Xe);
  transcvt_k<<<dim3(D_FF / 32, D_MODEL / 32, N_EXP), 256, 0, stream>>>(w1, w1t, D_MODEL, D_FF);
  transcvt_k<<<dim3(D_MODEL / 32, D_FF / 32, N_EXP), 256, 0, stream>>>(w2, w2t, D_FF, D_MODEL);

  moe_gemm_k<D_MODEL, D_FF, 1><<<dim3(D_FF / 128, 32, N_EXP), 256, 0, stream>>>(
      Xe, w1t, H, nullptr, counts, offsets, rowtok, rowwt);
  moe_gemm_k<D_FF, D_MODEL, 2><<<dim3(D_MODEL / 128, 32, N_EXP), 256, 0, stream>>>(
      H, w2t, nullptr, out, counts, offsets, rowtok, rowwt);
}

// Round 4
// 348.907 us; speedup vs baseline: 1.5026x; 1.0094x over previous
//
#include <hip/hip_runtime.h>
#include <cstdint>
#include <cstddef>

#define D_MODEL 1024
#define D_FF    2048
#define N_EXP   8
#define NTOK    4096          // B*S
#define NASSIGN (NTOK * 2)    // top-2

typedef __bf16 bf16_t;
typedef bf16_t bf16x8 __attribute__((ext_vector_type(8)));
typedef float  f32x4  __attribute__((ext_vector_type(4)));

typedef __attribute__((address_space(3))) void       lds_void;
typedef const __attribute__((address_space(1))) void gl_void;

__device__ __forceinline__ unsigned short f2b(float f) {
  union { float f; unsigned u; } v; v.f = f;
  unsigned u = v.u;
  unsigned r = (u + 0x7FFFu + ((u >> 16) & 1u)) >> 16;  // RNE
  return (unsigned short)r;
}
__device__ __forceinline__ float b2f(unsigned short b) {
  union { unsigned u; float f; } v; v.u = ((unsigned)b) << 16; return v.f;
}

// ---------------- Router: fp32 logits, top-2, softmax. NO atomics. ----------------
__global__ __launch_bounds__(256) void router_k(
    const float* __restrict__ x, const float* __restrict__ gw,
    int* __restrict__ eidx, float* __restrict__ ewt)
{
  const int wv = threadIdx.x >> 6, lane = threadIdx.x & 63;
  const int token = blockIdx.x * 4 + wv;
  const float4* xr4 = (const float4*)(x + (size_t)token * D_MODEL);
  const float4* gw4 = (const float4*)gw;

  float acc[8] = {};
  #pragma unroll
  for (int it = 0; it < 4; ++it) {
    float4 xv = xr4[it * 64 + lane];
    int d0 = it * 256 + lane * 4;
    #pragma unroll
    for (int i = 0; i < 4; ++i) {
      int d = d0 + i;
      float4 g0 = gw4[d * 2];
      float4 g1 = gw4[d * 2 + 1];
      float xs = (i == 0) ? xv.x : (i == 1) ? xv.y : (i == 2) ? xv.z : xv.w;
      acc[0] += xs * g0.x; acc[1] += xs * g0.y;
      acc[2] += xs * g0.z; acc[3] += xs * g0.w;
      acc[4] += xs * g1.x; acc[5] += xs * g1.y;
      acc[6] += xs * g1.z; acc[7] += xs * g1.w;
    }
  }
  #pragma unroll
  for (int m = 1; m < 64; m <<= 1) {
    #pragma unroll
    for (int k = 0; k < 8; ++k) acc[k] += __shfl_xor(acc[k], m);
  }
  if (lane == 0) {
    int i1 = 0; float v1 = acc[0];
    #pragma unroll
    for (int k = 1; k < 8; ++k) if (acc[k] > v1) { v1 = acc[k]; i1 = k; }
    int i2 = -1; float v2 = -1e30f;
    #pragma unroll
    for (int k = 0; k < 8; ++k) if (k != i1 && acc[k] > v2) { v2 = acc[k]; i2 = k; }
    float t  = __expf(v2 - v1);
    float w1 = 1.f / (1.f + t);
    float w2 = t * w1;
    eidx[token * 2 + 0] = i1; eidx[token * 2 + 1] = i2;
    ewt [token * 2 + 0] = w1; ewt [token * 2 + 1] = w2;
  }
}

// ------- Scan: deterministic per-expert ranking. 256 thr x 32 assigns, 2-pass. -------
__global__ __launch_bounds__(256) void scan_k(
    const int* __restrict__ eidx, const float* __restrict__ ewt,
    int* __restrict__ counts, int* __restrict__ offsets,
    int* __restrict__ rowtok, float* __restrict__ rowwt, int* __restrict__ rowof)
{
  __shared__ int hist[256][9];   // stride 9: max 2-way (free)
  __shared__ int soff[8];
  const int t = threadIdx.x;

  int local[8] = {};
  #pragma unroll 4
  for (int i = 0; i < 32; ++i) local[eidx[t * 32 + i]]++;
  #pragma unroll
  for (int e = 0; e < 8; ++e) hist[t][e] = local[e];
  __syncthreads();

  // inclusive scan over 256 threads, 8 experts in parallel
  for (int ofs = 1; ofs < 256; ofs <<= 1) {
    int v[8];
    if (t >= ofs) {
      #pragma unroll
      for (int e = 0; e < 8; ++e) v[e] = hist[t - ofs][e];
    }
    __syncthreads();
    if (t >= ofs) {
      #pragma unroll
      for (int e = 0; e < 8; ++e) hist[t][e] += v[e];
    }
    __syncthreads();
  }

  if (t == 0) {
    int o = 0;
    for (int e = 0; e < 8; ++e) {
      int c = hist[255][e];
      counts[e] = c;
      offsets[e] = o;
      soff[e] = o;
      o += c;
    }
  }
  __syncthreads();

  int run[8];
  #pragma unroll
  for (int e = 0; e < 8; ++e) run[e] = soff[e] + hist[t][e] - local[e];

  #pragma unroll 4
  for (int i = 0; i < 32; ++i) {
    int b = t * 32 + i;
    int e = eidx[b];
    int row = run[e]++;
    rowtok[row] = b >> 1;
    rowwt[row]  = ewt[b];
    rowof[b]    = row;
  }
}

// -------- Gather: block per row, x[token] -> bf16 Xe[row]. NO atomics. --------
__global__ __launch_bounds__(256) void gather_k(
    const float* __restrict__ x, const int* __restrict__ rowtok,
    unsigned short* __restrict__ Xe)
{
  const int row = blockIdx.x;
  const int token = rowtok[row];
  const float4* xr = (const float4*)(x + (size_t)token * D_MODEL);
  ushort4* dst = (ushort4*)(Xe + (size_t)row * D_MODEL);
  float4 v = xr[threadIdx.x];
  ushort4 o;
  o.x = f2b(v.x); o.y = f2b(v.y); o.z = f2b(v.z); o.w = f2b(v.w);
  dst[threadIdx.x] = o;
}

// ------- Transpose + fp32->bf16: in [e][R][C] -> out [e][C][R] -------
// 64x64 tile; float4 coalesced reads, ushort4 coalesced writes.
__global__ __launch_bounds__(256) void transcvt_k(
    const float* __restrict__ in, unsigned short* __restrict__ out, int R, int C)
{
  __shared__ float T[64][65];
  const int e = blockIdx.z;
  const float* ein = in + (size_t)e * R * C;
  unsigned short* eout = out + (size_t)e * R * C;
  const int c0 = blockIdx.x * 64, r0 = blockIdx.y * 64;
  const int g = threadIdx.x >> 4;        // 0..15
  const int m = threadIdx.x & 15;        // 0..15

  #pragma unroll
  for (int i = 0; i < 4; ++i) {
    int r = i * 16 + g;
    float4 v = *(const float4*)(ein + (size_t)(r0 + r) * C + c0 + m * 4);
    T[r][m * 4 + 0] = v.x; T[r][m * 4 + 1] = v.y;
    T[r][m * 4 + 2] = v.z; T[r][m * 4 + 3] = v.w;
  }
  __syncthreads();
  #pragma unroll
  for (int i = 0; i < 4; ++i) {
    int c = i * 16 + g;
    ushort4 o;
    o.x = f2b(T[m * 4 + 0][c]); o.y = f2b(T[m * 4 + 1][c]);
    o.z = f2b(T[m * 4 + 2][c]); o.w = f2b(T[m * 4 + 3][c]);
    *(ushort4*)(eout + (size_t)(c0 + c) * R + r0 + m * 4) = o;
  }
}

// ---------------- Segmented bf16 MFMA GEMM, 128x128x32 tiles ----------------
// A: [rows][K] bf16 (gathered segments). Bt: [E][N][K] bf16 (k-contiguous).
// MODE 1: Hout[row][N] = bf16(silu(A.Bt^T))
// MODE 2: Hout[row][N] = bf16(rowwt[row] * (A.Bt^T))   (plain stores, no atomics)
template<int K, int N, int MODE>
__global__ __launch_bounds__(256) void moe_gemm_k(
    const unsigned short* __restrict__ A,
    const unsigned short* __restrict__ Bt,
    unsigned short* __restrict__ Hout,
    const int* __restrict__ counts, const int* __restrict__ offsets,
    const float* __restrict__ rowwt)
{
  const int e = blockIdx.z;
  const int cnt = counts[e];
  const int m0 = blockIdx.y * 128;
  if (m0 >= cnt) return;
  const int base = offsets[e];
  const int n0 = blockIdx.x * 128;

  __shared__ unsigned short lA[128 * 32];
  __shared__ unsigned short lB[128 * 32];

  const int tid = threadIdx.x;
  const int lane = tid & 63;
  const int wv = tid >> 6;
  const int wm = wv & 1, wn = wv >> 1;
  const int col = lane & 15, quad = lane >> 4;

  const unsigned short* Aseg = A + (size_t)base * K;
  const unsigned short* Bseg = Bt + (size_t)e * ((size_t)N * K);

  f32x4 acc[4][4] = {};

  for (int k0 = 0; k0 < K; k0 += 32) {
    __syncthreads();
    #pragma unroll
    for (int r = 0; r < 2; ++r) {
      int flat = ((r * 4 + wv) * 64 + lane) * 16;   // byte offset within 8KB tile
      int row = flat >> 6;                          // 64B per (row, 32 k) slice
      int kb  = flat & 63;
      const char* gA = (const char*)Aseg + ((size_t)(m0 + row) * K + k0) * 2 + kb;
      const char* gB = (const char*)Bseg + ((size_t)(n0 + row) * K + k0) * 2 + kb;
      char* lpa = (char*)lA + (r * 4 + wv) * 1024;
      char* lpb = (char*)lB + (r * 4 + wv) * 1024;
      __builtin_amdgcn_global_load_lds((gl_void*)gA, (lds_void*)lpa, 16, 0, 0);
      __builtin_amdgcn_global_load_lds((gl_void*)gB, (lds_void*)lpb, 16, 0, 0);
    }
    __syncthreads();

    bf16x8 af[4], bfr[4];
    #pragma unroll
    for (int i = 0; i < 4; ++i)
      af[i] = *(const bf16x8*)(lA + ((wm * 64 + i * 16 + col) * 32 + quad * 8));
    #pragma unroll
    for (int j = 0; j < 4; ++j)
      bfr[j] = *(const bf16x8*)(lB + ((wn * 64 + j * 16 + col) * 32 + quad * 8));
    #pragma unroll
    for (int i = 0; i < 4; ++i)
      #pragma unroll
      for (int j = 0; j < 4; ++j)
        acc[i][j] = __builtin_amdgcn_mfma_f32_16x16x32_bf16(af[i], bfr[j], acc[i][j], 0, 0, 0);
  }

  // Epilogue. C/D layout: col = lane&15, row = quad*4 + reg  [m89/m91 verified]
  #pragma unroll
  for (int i = 0; i < 4; ++i) {
    #pragma unroll
    for (int reg = 0; reg < 4; ++reg) {
      int r = m0 + wm * 64 + i * 16 + quad * 4 + reg;
      if (r < cnt) {
        unsigned short* hrow = Hout + (size_t)(base + r) * N + (n0 + wn * 64 + col);
        if (MODE == 1) {
          #pragma unroll
          for (int j = 0; j < 4; ++j) {
            float v = acc[i][j][reg];
            float s = v / (1.f + __expf(-v));   // silu
            hrow[j * 16] = f2b(s);
          }
        } else {
          float wgt = rowwt[base + r];
          #pragma unroll
          for (int j = 0; j < 4; ++j)
            hrow[j * 16] = f2b(wgt * acc[i][j][reg]);
        }
      }
    }
  }
}

// ------- Combine: out[t] = Y[rowof[2t]] + Y[rowof[2t+1]] (weights pre-applied) -------
__global__ __launch_bounds__(256) void combine_k(
    const unsigned short* __restrict__ Y, const int* __restrict__ rowof,
    float* __restrict__ out)
{
  const int token = blockIdx.x;
  const int r1 = rowof[token * 2];
  const int r2 = rowof[token * 2 + 1];
  const int d4 = threadIdx.x;   // 256 threads x 4 floats = 1024
  ushort4 a = *(const ushort4*)(Y + (size_t)r1 * D_MODEL + d4 * 4);
  ushort4 b = *(const ushort4*)(Y + (size_t)r2 * D_MODEL + d4 * 4);
  float4 o;
  o.x = b2f(a.x) + b2f(b.x);
  o.y = b2f(a.y) + b2f(b.y);
  o.z = b2f(a.z) + b2f(b.z);
  o.w = b2f(a.w) + b2f(b.w);
  *(float4*)(out + (size_t)token * D_MODEL + d4 * 4) = o;
}

extern "C" void kernel_launch(void* const* d_in, const int* in_sizes, int n_in,
                              void* d_out, int out_size, void* d_ws, size_t ws_size,
                              hipStream_t stream) {
  const float* x  = (const float*)d_in[0];
  const float* gw = (const float*)d_in[1];
  const float* w1 = (const float*)d_in[2];
  const float* w2 = (const float*)d_in[3];
  float* out = (float*)d_out;

  char* ws = (char*)d_ws;
  size_t off = 0;
  auto alloc = [&](size_t bytes) -> char* {
    char* p = ws + off; off += (bytes + 255) & ~(size_t)255; return p;
  };
  int*   ctrl    = (int*)alloc(256);      // counts[8] | offsets[8]
  int*   counts  = ctrl;
  int*   offsets = ctrl + 8;
  int*   eidx    = (int*)  alloc((size_t)NASSIGN * 4);
  float* ewt     = (float*)alloc((size_t)NASSIGN * 4);
  int*   rowtok  = (int*)  alloc((size_t)NASSIGN * 4);
  float* rowwt   = (float*)alloc((size_t)NASSIGN * 4);
  int*   rowof   = (int*)  alloc((size_t)NASSIGN * 4);
  unsigned short* Xe  = (unsigned short*)alloc((size_t)(NASSIGN + 128) * D_MODEL * 2);
  unsigned short* H   = (unsigned short*)alloc((size_t)(NASSIGN + 128) * D_FF * 2);
  unsigned short* Y   = (unsigned short*)alloc((size_t)(NASSIGN + 128) * D_MODEL * 2);
  unsigned short* w1t = (unsigned short*)alloc((size_t)N_EXP * D_MODEL * D_FF * 2);
  unsigned short* w2t = (unsigned short*)alloc((size_t)N_EXP * D_MODEL * D_FF * 2);

  router_k<<<NTOK / 4, 256, 0, stream>>>(x, gw, eidx, ewt);
  scan_k<<<1, 256, 0, stream>>>(eidx, ewt, counts, offsets, rowtok, rowwt, rowof);
  gather_k<<<NASSIGN, 256, 0, stream>>>(x, rowtok, Xe);
  transcvt_k<<<dim3(D_FF / 64, D_MODEL / 64, N_EXP), 256, 0, stream>>>(w1, w1t, D_MODEL, D_FF);
  transcvt_k<<<dim3(D_MODEL / 64, D_FF / 64, N_EXP), 256, 0, stream>>>(w2, w2t, D_FF, D_MODEL);

  moe_gemm_k<D_MODEL, D_FF, 1><<<dim3(D_FF / 128, 32, N_EXP), 256, 0, stream>>>(
      Xe, w1t, H, counts, offsets, rowwt);
  moe_gemm_k<D_FF, D_MODEL, 2><<<dim3(D_MODEL / 128, 32, N_EXP), 256, 0, stream>>>(
      H, w2t, Y, counts, offsets, rowwt);
  combine_k<<<NTOK, 256, 0, stream>>>(Y, rowof, out);
}